// Round 7
// baseline (182.591 us; speedup 1.0000x reference)
//
#include <hip/hip_runtime.h>
#include <stdint.h>
#include <math.h>

typedef unsigned short u16;
typedef float f32x4 __attribute__((ext_vector_type(4)));
typedef __bf16 bf16x8 __attribute__((ext_vector_type(8)));

__device__ __forceinline__ u16 f2bf(float f) {
    union { float f; uint32_t u; } c; c.f = f;
    return (u16)((c.u + 0x7FFFu + ((c.u >> 16) & 1u)) >> 16);
}

__device__ __forceinline__ void gload_lds16(const void* g, void* l) {
    __builtin_amdgcn_global_load_lds(
        (const __attribute__((address_space(1))) unsigned int*)g,
        (__attribute__((address_space(3))) unsigned int*)l, 16, 0, 0);
}

// --------- fused prep: LN (blocks 0..4095) + w_qkv transpose (next 1536)
// --------- + w_proj transpose (last 512). All roles block-uniform.
__global__ __launch_bounds__(256) void prep_kernel(const float* __restrict__ z,
                                                   const float* __restrict__ sc,
                                                   const float* __restrict__ bs,
                                                   const float* __restrict__ w_qkv,
                                                   const float* __restrict__ w_proj,
                                                   u16* __restrict__ zn,
                                                   u16* __restrict__ wqkvT,
                                                   u16* __restrict__ wprojT) {
    __shared__ __align__(16) float t[32][68];
    const int tid = threadIdx.x;
    const int bid = blockIdx.x;

    if (bid < 4096) {                      // ---- LayerNorm row
        float* red = &t[0][0];
        const int row = bid;
        const float4 v = ((const float4*)(z + (size_t)row * 1024))[tid];
        float s = v.x + v.y + v.z + v.w;
        #pragma unroll
        for (int off = 32; off > 0; off >>= 1) s += __shfl_xor(s, off);
        if ((tid & 63) == 0) red[tid >> 6] = s;
        __syncthreads();
        const float mean = (red[0] + red[1] + red[2] + red[3]) * (1.0f / 1024.0f);
        const float dx = v.x - mean, dy = v.y - mean, dz = v.z - mean, dw = v.w - mean;
        float q = dx * dx + dy * dy + dz * dz + dw * dw;
        #pragma unroll
        for (int off = 32; off > 0; off >>= 1) q += __shfl_xor(q, off);
        if ((tid & 63) == 0) red[4 + (tid >> 6)] = q;
        __syncthreads();
        const float var = (red[4] + red[5] + red[6] + red[7]) * (1.0f / 1024.0f);
        const float rstd = rsqrtf(var + 1e-5f);
        const float4 scv = ((const float4*)sc)[tid];
        const float4 bsv = ((const float4*)bs)[tid];
        const u16 o0 = f2bf(dx * rstd * scv.x + bsv.x);
        const u16 o1 = f2bf(dy * rstd * scv.y + bsv.y);
        const u16 o2 = f2bf(dz * rstd * scv.z + bsv.z);
        const u16 o3 = f2bf(dw * rstd * scv.w + bsv.w);
        uint2 pk;
        pk.x = (uint32_t)o0 | ((uint32_t)o1 << 16);
        pk.y = (uint32_t)o2 | ((uint32_t)o3 << 16);
        *(uint2*)&zn[(size_t)row * 1024 + tid * 4] = pk;
        return;
    }

    const float* in;
    u16* out;
    int N, permute, bx, by;
    if (bid < 4096 + 1536) {               // w_qkv: [1024,3072] -> permuted [3072,1024]
        const int r = bid - 4096;
        in = w_qkv; out = wqkvT; N = 3072; permute = 1;
        bx = r % 48; by = r / 48;
    } else {                               // w_proj: [1024,1024] -> [1024,1024]
        const int r = bid - 4096 - 1536;
        in = w_proj; out = wprojT; N = 1024; permute = 0;
        bx = r % 16; by = r / 16;
    }
    const int kb = by * 32, nb = bx * 64;
    const int lr = tid >> 3, lq = tid & 7;
    const float* src = &in[(size_t)(kb + lr) * N + nb + lq * 8];
    const float4 va = *(const float4*)src;
    const float4 vb = *(const float4*)(src + 4);
    *(float4*)&t[lr][lq * 8] = va;
    *(float4*)&t[lr][lq * 8 + 4] = vb;
    __syncthreads();
    const int cj = tid >> 6, c = tid & 63;
    const int col = nb + c;
    int np = col;
    if (permute) {
        const int h = col / 192, rem = col - h * 192;
        const int d = rem / 3, s = rem - d * 3;
        np = s * 1024 + h * 64 + d;
    }
    u16 pk[8];
    #pragma unroll
    for (int u = 0; u < 8; ++u) pk[u] = f2bf(t[cj * 8 + u][c]);
    *(uint4*)&out[(size_t)np * 1024 + kb + cj * 8] = *(const uint4*)pk;
}

// ---------------- GEMM1 (R6 two-barrier) + fused V transpose ---------------
__global__ __launch_bounds__(256, 3) void gemm_qkv(const u16* __restrict__ A,
                                                   const u16* __restrict__ Bt,
                                                   u16* __restrict__ qbuf,
                                                   u16* __restrict__ kbuf,
                                                   u16* __restrict__ vT) {
    __shared__ __align__(16) u16 sm[64 * 136];   // 17.4 KB; main loop uses [0,8192)
    u16* const As = sm;                           // 128*32
    u16* const Bs = sm + 4096;                    // 128*32
    const int tid = threadIdx.x;
    const int wave = tid >> 6, lane = tid & 63;
    const int quad = lane >> 4, l16 = lane & 15;
    const int wm = (wave >> 1) * 64, wn = (wave & 1) * 64;
    const int lin = blockIdx.y * 32 + blockIdx.x;           // 0..767
    const int nlin = (lin & 7) * 96 + (lin >> 3);           // bijective (768%8==0)
    const int bxs = nlin & 31, bys = nlin >> 5;
    const int row0 = bxs * 128, col0 = bys * 128;
    const int gr = lane >> 2, gc = (lane & 3) * 8;
    f32x4 acc[4][4] = {};
    for (int kt = 0; kt < 1024; kt += 32) {
        __syncthreads();
        #pragma unroll
        for (int i = 0; i < 2; ++i) {
            const int rb = wave * 16 + i * 64;
            gload_lds16(&A[(size_t)(row0 + rb + gr) * 1024 + kt + gc], &As[rb * 32]);
            gload_lds16(&Bt[(size_t)(col0 + rb + gr) * 1024 + kt + gc], &Bs[rb * 32]);
        }
        __syncthreads();
        bf16x8 ax[4], bx[4];
        #pragma unroll
        for (int t = 0; t < 4; ++t) {
            ax[t] = *(const bf16x8*)&As[(wm + t * 16 + l16) * 32 + quad * 8];
            bx[t] = *(const bf16x8*)&Bs[(wn + t * 16 + l16) * 32 + quad * 8];
        }
        #pragma unroll
        for (int mt = 0; mt < 4; ++mt)
            #pragma unroll
            for (int nt = 0; nt < 4; ++nt)
                acc[mt][nt] = __builtin_amdgcn_mfma_f32_16x16x32_bf16(ax[mt], bx[nt], acc[mt][nt], 0, 0, 0);
    }
    const int s = col0 >> 10;                 // block-uniform
    if (s < 2) {
        u16* const dst = (s == 0) ? qbuf : kbuf;
        const float scl = (s == 0) ? 0.125f * 1.44269504088896f : 1.0f;
        #pragma unroll
        for (int mt = 0; mt < 4; ++mt) {
            #pragma unroll
            for (int nt = 0; nt < 4; ++nt) {
                #pragma unroll
                for (int e = 0; e < 4; ++e) {
                    const int row = row0 + wm + mt * 16 + quad * 4 + e;
                    const int col = col0 + wn + nt * 16 + l16;
                    const int b = row >> 11, n = row & 2047;
                    const int h = (col >> 6) & 15, d = col & 63;
                    dst[((size_t)(b * 16 + h) * 2048 + n) * 64 + d] = f2bf(acc[mt][nt][e] * scl);
                }
            }
        }
    } else {
        // V: transpose 128x128 tile through LDS, store to vT[bh,d,n].
        const int b = row0 >> 11, n0 = row0 & 2047;
        const int h0 = (col0 >> 6) & 15;          // col0 = 2048 + cb*128 -> h0 = 2*cb
        for (int hh = 0; hh < 2; ++hh) {
            __syncthreads();                      // tile buffer free (main loop / prev pass done)
            if ((wave & 1) == hh) {               // wn == hh*64 waves own this col-half
                #pragma unroll
                for (int mt = 0; mt < 4; ++mt) {
                    const int rl = wm + mt * 16 + quad * 4;       // multiple of 4 -> 8B aligned
                    #pragma unroll
                    for (int nt = 0; nt < 4; ++nt) {
                        const int cl = nt * 16 + l16;             // d 0..63
                        u16 tmp[4];
                        #pragma unroll
                        for (int e = 0; e < 4; ++e) tmp[e] = f2bf(acc[mt][nt][e]);
                        *(uint2*)&sm[cl * 136 + rl] = *(const uint2*)tmp;   // ds_write_b64
                    }
                }
            }
            __syncthreads();
            const int bh = b * 16 + h0 + hh;
            #pragma unroll
            for (int pass = 0; pass < 4; ++pass) {
                const int chunk = pass * 256 + tid;   // 0..1023
                const int d = chunk >> 4;             // 0..63
                const int nc = chunk & 15;            // 16 chunks of 8 n
                const uint4 vv = *(const uint4*)&sm[d * 136 + nc * 8];
                *(uint4*)&vT[((size_t)bh * 64 + d) * 2048 + n0 + nc * 8] = vv;
            }
        }
    }
}

// ---------------- Fused flash attention — R21: KVBLK=64, 4 blocks/CU -------
// (R22 = R21 resubmit: R6 bench died with an infra error, no verdict. Kernel
// re-audited: kr bit-permutation stays in [0,64) (bit5=c fixed), PV closure
// re-derived exact, V swizzle XORs cancel, LDS 4x32KB=128<=160KB, uniform
// barriers. No hang mechanism; resubmitting unchanged.)
// R5 post-mortem: FETCH fixed (69->12MB) but time flat -> not memory-bound.
// MfmaUtil 38 + VALUBusy 38 = 76% combined at 2 waves/SIMD = random-phase
// coverage limit. Fix: halve tile (KVBLK=64, QBLK=64): LDS 32KB -> 4
// blocks/CU (grid 32x32 = 1024 = exactly 4/CU), 4 waves/SIMD -> ~94%.
__global__ __launch_bounds__(256, 4) void attn_kernel(const u16* __restrict__ qb,
                                                      const u16* __restrict__ kb,
                                                      const u16* __restrict__ vT,
                                                      u16* __restrict__ att_out) {
    __shared__ __align__(16) u16 smem[2][8192];   // [buf][Ks 64*64 | Vs 64*64]
    const int tid = threadIdx.x;
    const int wave = tid >> 6, lane = tid & 63;
    const int quad = lane >> 4, l16 = lane & 15;
    const int lin = blockIdx.y * 32 + blockIdx.x;          // 0..1023
    const int nlin = (lin & 7) * 128 + (lin >> 3);         // bijective (1024%8==0)
    const int qt = nlin & 31, bh = nlin >> 5;
    const int b = bh >> 4, h = bh & 15;

    // this wave's 16 q rows, all of d=0..63 (pre-scaled 0.125*log2e)
    const u16* qrow = &qb[(size_t)(bh * 2048 + qt * 64 + wave * 16 + l16) * 64];
    const bf16x8 qA0 = *(const bf16x8*)&qrow[quad * 8];
    const bf16x8 qA1 = *(const bf16x8*)&qrow[32 + quad * 8];

    const u16* ksrc[2];
    const u16* vsrc[2];
    int kofs[2], vofs[2];
    #pragma unroll
    for (int j = 0; j < 2; ++j) {
        const int p = 8 * wave + 32 * j + (lane >> 3);      // 0..63 row slot
        const int kr = (p & 0x60) | ((p & 12) << 1) | ((p & 16) >> 2) | (p & 3);
        const int gk = (lane & 7) ^ (p & 7);
        ksrc[j] = kb + ((size_t)bh * 2048 + kr) * 64 + gk * 8;
        kofs[j] = (8 * wave + 32 * j) * 64;
        const int d = 8 * wave + 32 * j + (lane >> 3);      // 0..63
        const int gv = (lane & 7) ^ ((d >> 1) & 7);
        vsrc[j] = vT + ((size_t)bh * 64 + d) * 2048 + gv * 8;
        vofs[j] = 4096 + (8 * wave + 32 * j) * 64;
    }

    f32x4 oA[4] = {};
    f32x4 lA = {};
    bf16x8 ones;
    #pragma unroll
    for (int i = 0; i < 8; ++i) ones[i] = (__bf16)1.0f;

    #pragma unroll
    for (int j = 0; j < 2; ++j) {
        gload_lds16(ksrc[j], &smem[0][kofs[j]]);
        gload_lds16(vsrc[j], &smem[0][vofs[j]]);
        ksrc[j] += 64 * 64;
        vsrc[j] += 64;
    }

    for (int kt = 0; kt < 32; ++kt) {
        __syncthreads();
        if (kt < 31) {
            u16* nb_ = smem[(kt + 1) & 1];
            #pragma unroll
            for (int j = 0; j < 2; ++j) {
                gload_lds16(ksrc[j], &nb_[kofs[j]]);
                gload_lds16(vsrc[j], &nb_[vofs[j]]);
                ksrc[j] += 64 * 64;
                vsrc[j] += 64;
            }
        }
        const u16* Ks = smem[kt & 1];
        const u16* Vs = smem[kt & 1] + 4096;

        f32x4 sA[4] = {};
        __builtin_amdgcn_s_setprio(1);
        #pragma unroll
        for (int nt = 0; nt < 4; ++nt) {
            const int r = nt * 16 + l16;
            const bf16x8 k0 = *(const bf16x8*)&Ks[r * 64 + (((quad) ^ (r & 7)) << 3)];
            const bf16x8 k1 = *(const bf16x8*)&Ks[r * 64 + (((quad + 4) ^ (r & 7)) << 3)];
            sA[nt] = __builtin_amdgcn_mfma_f32_16x16x32_bf16(k0, qA0, sA[nt], 0, 0, 0);
            sA[nt] = __builtin_amdgcn_mfma_f32_16x16x32_bf16(k1, qA1, sA[nt], 0, 0, 0);
        }
        __builtin_amdgcn_s_setprio(0);

        bf16x8 ap[2];
        #pragma unroll
        for (int nt = 0; nt < 4; ++nt)
            #pragma unroll
            for (int e = 0; e < 4; ++e)
                ap[nt >> 1][(nt & 1) * 4 + e] = (__bf16)__builtin_amdgcn_exp2f(sA[nt][e]);

        __builtin_amdgcn_s_setprio(1);
        #pragma unroll
        for (int vt = 0; vt < 4; ++vt) {
            const int dd = vt * 16 + l16;
            #pragma unroll
            for (int c = 0; c < 2; ++c) {
                const bf16x8 vf = *(const bf16x8*)&Vs[dd * 64 + (((c * 4 + quad) ^ ((dd >> 1) & 7)) << 3)];
                oA[vt] = __builtin_amdgcn_mfma_f32_16x16x32_bf16(ap[c], vf, oA[vt], 0, 0, 0);
            }
        }
        #pragma unroll
        for (int c = 0; c < 2; ++c)
            lA = __builtin_amdgcn_mfma_f32_16x16x32_bf16(ap[c], ones, lA, 0, 0, 0);
        __builtin_amdgcn_s_setprio(0);
    }

    #pragma unroll
    for (int e = 0; e < 4; ++e) {
        const float invA = 1.0f / lA[e];
        const int nA = qt * 64 + wave * 16 + quad * 4 + e;
        #pragma unroll
        for (int vt = 0; vt < 4; ++vt)
            att_out[(size_t)(b * 2048 + nA) * 1024 + h * 64 + vt * 16 + l16] = f2bf(oA[vt][e] * invA);
    }
}

// ---- GEMM2 (R19 128x128) + R20 XCD swizzle: each XCD owns 1 B-panel ----
__global__ __launch_bounds__(256, 3) void gemm_proj(const u16* __restrict__ A,
                                                    const u16* __restrict__ Bt,
                                                    const float* __restrict__ bias,
                                                    const float* __restrict__ z,
                                                    float* __restrict__ out) {
    __shared__ __align__(16) u16 sm[2 * 4096];
    u16* const As = sm;                           // 128*32
    u16* const Bs = sm + 4096;                    // 128*32
    const int tid = threadIdx.x;
    const int wave = tid >> 6, lane = tid & 63;
    const int quad = lane >> 4, l16 = lane & 15;
    const int wm = (wave >> 1) * 64, wn = (wave & 1) * 64;
    const int lin = blockIdx.y * 32 + blockIdx.x;          // 0..255
    const int nlin = (lin & 7) * 32 + (lin >> 3);          // bijective (256%8==0)
    const int bxs = nlin & 31, bys = nlin >> 5;
    const int row0 = bxs * 128, col0 = bys * 128;
    const int gr = lane >> 2, gc = (lane & 3) * 8;
    f32x4 acc[4][4] = {};
    for (int kt = 0; kt < 1024; kt += 32) {
        __syncthreads();
        #pragma unroll
        for (int i = 0; i < 2; ++i) {
            const int rb = wave * 16 + i * 64;
            gload_lds16(&A[(size_t)(row0 + rb + gr) * 1024 + kt + gc], &As[rb * 32]);
            gload_lds16(&Bt[(size_t)(col0 + rb + gr) * 1024 + kt + gc], &Bs[rb * 32]);
        }
        __syncthreads();
        bf16x8 ax[4], bx[4];
        #pragma unroll
        for (int t = 0; t < 4; ++t) {
            ax[t] = *(const bf16x8*)&As[(wm + t * 16 + l16) * 32 + quad * 8];
            bx[t] = *(const bf16x8*)&Bs[(wn + t * 16 + l16) * 32 + quad * 8];
        }
        #pragma unroll
        for (int mt = 0; mt < 4; ++mt)
            #pragma unroll
            for (int nt = 0; nt < 4; ++nt)
                acc[mt][nt] = __builtin_amdgcn_mfma_f32_16x16x32_bf16(ax[mt], bx[nt], acc[mt][nt], 0, 0, 0);
    }
    #pragma unroll
    for (int mt = 0; mt < 4; ++mt) {
        #pragma unroll
        for (int nt = 0; nt < 4; ++nt) {
            #pragma unroll
            for (int e = 0; e < 4; ++e) {
                const int row = row0 + wm + mt * 16 + quad * 4 + e;
                const int col = col0 + wn + nt * 16 + l16;
                out[(size_t)row * 1024 + col] = acc[mt][nt][e] + bias[col] + z[(size_t)row * 1024 + col];
            }
        }
    }
}

extern "C" void kernel_launch(void* const* d_in, const int* in_sizes, int n_in,
                              void* d_out, int out_size, void* d_ws, size_t ws_size,
                              hipStream_t stream) {
    const float* z        = (const float*)d_in[0];
    const float* ln_scale = (const float*)d_in[1];
    const float* ln_bias  = (const float*)d_in[2];
    const float* w_qkv    = (const float*)d_in[3];
    const float* w_proj   = (const float*)d_in[4];
    const float* b_proj   = (const float*)d_in[5];
    float* out = (float*)d_out;

    char* ws = (char*)d_ws;
    u16* zn     = (u16*)(ws);                       // 0-8 MiB   [4096,1024]
    u16* wqkvT  = (u16*)(ws + (8u << 20));          // 8-14 MiB  [3072,1024] (rows permuted)
    u16* wprojT = (u16*)(ws + (14u << 20));         // 14-16 MiB [1024,1024]
    u16* qbuf   = (u16*)(ws + (16u << 20));         // 16-24 MiB [32,2048,64] (pre-scaled 0.125*log2e)
    u16* kbuf   = (u16*)(ws + (24u << 20));         // 24-32 MiB [32,2048,64]
    u16* vT     = (u16*)(ws + (32u << 20));         // 32-40 MiB [32,64,2048] (written by gemm_qkv)
    u16* att_o  = (u16*)(ws + (40u << 20));         // 40-48 MiB [4096,1024]

    prep_kernel<<<dim3(4096 + 1536 + 512), 256, 0, stream>>>(
        z, ln_scale, ln_bias, w_qkv, w_proj, zn, wqkvT, wprojT);
    gemm_qkv<<<dim3(32, 24), 256, 0, stream>>>(zn, wqkvT, qbuf, kbuf, vT);
    attn_kernel<<<dim3(32, 32), 256, 0, stream>>>(qbuf, kbuf, vT, att_o);
    gemm_proj<<<dim3(32, 8), 256, 0, stream>>>(att_o, wprojT, b_proj, z, out);
}

// Round 8
// 179.812 us; speedup vs baseline: 1.0155x; 1.0155x over previous
//
#include <hip/hip_runtime.h>
#include <stdint.h>
#include <math.h>

typedef unsigned short u16;
typedef float f32x4 __attribute__((ext_vector_type(4)));
typedef __bf16 bf16x8 __attribute__((ext_vector_type(8)));

__device__ __forceinline__ u16 f2bf(float f) {
    union { float f; uint32_t u; } c; c.f = f;
    return (u16)((c.u + 0x7FFFu + ((c.u >> 16) & 1u)) >> 16);
}

__device__ __forceinline__ void gload_lds16(const void* g, void* l) {
    __builtin_amdgcn_global_load_lds(
        (const __attribute__((address_space(1))) unsigned int*)g,
        (__attribute__((address_space(3))) unsigned int*)l, 16, 0, 0);
}

// --------- fused prep: LN (blocks 0..4095) + w_qkv transpose (next 1536)
// --------- + w_proj transpose (last 512). All roles block-uniform.
__global__ __launch_bounds__(256) void prep_kernel(const float* __restrict__ z,
                                                   const float* __restrict__ sc,
                                                   const float* __restrict__ bs,
                                                   const float* __restrict__ w_qkv,
                                                   const float* __restrict__ w_proj,
                                                   u16* __restrict__ zn,
                                                   u16* __restrict__ wqkvT,
                                                   u16* __restrict__ wprojT) {
    __shared__ __align__(16) float t[32][68];
    const int tid = threadIdx.x;
    const int bid = blockIdx.x;

    if (bid < 4096) {                      // ---- LayerNorm row
        float* red = &t[0][0];
        const int row = bid;
        const float4 v = ((const float4*)(z + (size_t)row * 1024))[tid];
        float s = v.x + v.y + v.z + v.w;
        #pragma unroll
        for (int off = 32; off > 0; off >>= 1) s += __shfl_xor(s, off);
        if ((tid & 63) == 0) red[tid >> 6] = s;
        __syncthreads();
        const float mean = (red[0] + red[1] + red[2] + red[3]) * (1.0f / 1024.0f);
        const float dx = v.x - mean, dy = v.y - mean, dz = v.z - mean, dw = v.w - mean;
        float q = dx * dx + dy * dy + dz * dz + dw * dw;
        #pragma unroll
        for (int off = 32; off > 0; off >>= 1) q += __shfl_xor(q, off);
        if ((tid & 63) == 0) red[4 + (tid >> 6)] = q;
        __syncthreads();
        const float var = (red[4] + red[5] + red[6] + red[7]) * (1.0f / 1024.0f);
        const float rstd = rsqrtf(var + 1e-5f);
        const float4 scv = ((const float4*)sc)[tid];
        const float4 bsv = ((const float4*)bs)[tid];
        const u16 o0 = f2bf(dx * rstd * scv.x + bsv.x);
        const u16 o1 = f2bf(dy * rstd * scv.y + bsv.y);
        const u16 o2 = f2bf(dz * rstd * scv.z + bsv.z);
        const u16 o3 = f2bf(dw * rstd * scv.w + bsv.w);
        uint2 pk;
        pk.x = (uint32_t)o0 | ((uint32_t)o1 << 16);
        pk.y = (uint32_t)o2 | ((uint32_t)o3 << 16);
        *(uint2*)&zn[(size_t)row * 1024 + tid * 4] = pk;
        return;
    }

    const float* in;
    u16* out;
    int N, permute, bx, by;
    if (bid < 4096 + 1536) {               // w_qkv: [1024,3072] -> permuted [3072,1024]
        const int r = bid - 4096;
        in = w_qkv; out = wqkvT; N = 3072; permute = 1;
        bx = r % 48; by = r / 48;
    } else {                               // w_proj: [1024,1024] -> [1024,1024]
        const int r = bid - 4096 - 1536;
        in = w_proj; out = wprojT; N = 1024; permute = 0;
        bx = r % 16; by = r / 16;
    }
    const int kb = by * 32, nb = bx * 64;
    const int lr = tid >> 3, lq = tid & 7;
    const float* src = &in[(size_t)(kb + lr) * N + nb + lq * 8];
    const float4 va = *(const float4*)src;
    const float4 vb = *(const float4*)(src + 4);
    *(float4*)&t[lr][lq * 8] = va;
    *(float4*)&t[lr][lq * 8 + 4] = vb;
    __syncthreads();
    const int cj = tid >> 6, c = tid & 63;
    const int col = nb + c;
    int np = col;
    if (permute) {
        const int h = col / 192, rem = col - h * 192;
        const int d = rem / 3, s = rem - d * 3;
        np = s * 1024 + h * 64 + d;
    }
    u16 pk[8];
    #pragma unroll
    for (int u = 0; u < 8; ++u) pk[u] = f2bf(t[cj * 8 + u][c]);
    *(uint4*)&out[(size_t)np * 1024 + kb + cj * 8] = *(const uint4*)pk;
}

// ---------------- GEMM1 (R6 two-barrier) + fused V transpose ---------------
__global__ __launch_bounds__(256, 3) void gemm_qkv(const u16* __restrict__ A,
                                                   const u16* __restrict__ Bt,
                                                   u16* __restrict__ qbuf,
                                                   u16* __restrict__ kbuf,
                                                   u16* __restrict__ vT) {
    __shared__ __align__(16) u16 sm[64 * 136];   // 17.4 KB; main loop uses [0,8192)
    u16* const As = sm;                           // 128*32
    u16* const Bs = sm + 4096;                    // 128*32
    const int tid = threadIdx.x;
    const int wave = tid >> 6, lane = tid & 63;
    const int quad = lane >> 4, l16 = lane & 15;
    const int wm = (wave >> 1) * 64, wn = (wave & 1) * 64;
    const int lin = blockIdx.y * 32 + blockIdx.x;           // 0..767
    const int nlin = (lin & 7) * 96 + (lin >> 3);           // bijective (768%8==0)
    const int bxs = nlin & 31, bys = nlin >> 5;
    const int row0 = bxs * 128, col0 = bys * 128;
    const int gr = lane >> 2, gc = (lane & 3) * 8;
    f32x4 acc[4][4] = {};
    for (int kt = 0; kt < 1024; kt += 32) {
        __syncthreads();
        #pragma unroll
        for (int i = 0; i < 2; ++i) {
            const int rb = wave * 16 + i * 64;
            gload_lds16(&A[(size_t)(row0 + rb + gr) * 1024 + kt + gc], &As[rb * 32]);
            gload_lds16(&Bt[(size_t)(col0 + rb + gr) * 1024 + kt + gc], &Bs[rb * 32]);
        }
        __syncthreads();
        bf16x8 ax[4], bx[4];
        #pragma unroll
        for (int t = 0; t < 4; ++t) {
            ax[t] = *(const bf16x8*)&As[(wm + t * 16 + l16) * 32 + quad * 8];
            bx[t] = *(const bf16x8*)&Bs[(wn + t * 16 + l16) * 32 + quad * 8];
        }
        #pragma unroll
        for (int mt = 0; mt < 4; ++mt)
            #pragma unroll
            for (int nt = 0; nt < 4; ++nt)
                acc[mt][nt] = __builtin_amdgcn_mfma_f32_16x16x32_bf16(ax[mt], bx[nt], acc[mt][nt], 0, 0, 0);
    }
    const int s = col0 >> 10;                 // block-uniform
    if (s < 2) {
        u16* const dst = (s == 0) ? qbuf : kbuf;
        const float scl = (s == 0) ? 0.125f * 1.44269504088896f : 1.0f;
        #pragma unroll
        for (int mt = 0; mt < 4; ++mt) {
            #pragma unroll
            for (int nt = 0; nt < 4; ++nt) {
                #pragma unroll
                for (int e = 0; e < 4; ++e) {
                    const int row = row0 + wm + mt * 16 + quad * 4 + e;
                    const int col = col0 + wn + nt * 16 + l16;
                    const int b = row >> 11, n = row & 2047;
                    const int h = (col >> 6) & 15, d = col & 63;
                    dst[((size_t)(b * 16 + h) * 2048 + n) * 64 + d] = f2bf(acc[mt][nt][e] * scl);
                }
            }
        }
    } else {
        // V: transpose 128x128 tile through LDS, store to vT[bh,d,n].
        const int b = row0 >> 11, n0 = row0 & 2047;
        const int h0 = (col0 >> 6) & 15;          // col0 = 2048 + cb*128 -> h0 = 2*cb
        for (int hh = 0; hh < 2; ++hh) {
            __syncthreads();                      // tile buffer free (main loop / prev pass done)
            if ((wave & 1) == hh) {               // wn == hh*64 waves own this col-half
                #pragma unroll
                for (int mt = 0; mt < 4; ++mt) {
                    const int rl = wm + mt * 16 + quad * 4;       // multiple of 4 -> 8B aligned
                    #pragma unroll
                    for (int nt = 0; nt < 4; ++nt) {
                        const int cl = nt * 16 + l16;             // d 0..63
                        u16 tmp[4];
                        #pragma unroll
                        for (int e = 0; e < 4; ++e) tmp[e] = f2bf(acc[mt][nt][e]);
                        *(uint2*)&sm[cl * 136 + rl] = *(const uint2*)tmp;   // ds_write_b64
                    }
                }
            }
            __syncthreads();
            const int bh = b * 16 + h0 + hh;
            #pragma unroll
            for (int pass = 0; pass < 4; ++pass) {
                const int chunk = pass * 256 + tid;   // 0..1023
                const int d = chunk >> 4;             // 0..63
                const int nc = chunk & 15;            // 16 chunks of 8 n
                const uint4 vv = *(const uint4*)&sm[d * 136 + nc * 8];
                *(uint4*)&vT[((size_t)bh * 64 + d) * 2048 + n0 + nc * 8] = vv;
            }
        }
    }
}

// -------- Fused flash attention — R23: 2-deep S-pipeline (dep-break) -------
// R7 post-mortem: MFMA-busy (16.4us) + VALU-busy (18.8us) ~= dur (44.8us):
// the pipes SERIALIZE because exp(t) depends on QK(t) and PV(t) on exp(t)
// within each iteration — waves stall on the chain, and occupancy/setprio
// can't fix a dependence. Fix: compute exp+PV of tile t-1 WHILE QK of tile
// t runs (2-deep S state, ping-pong s0/s1 via explicit pair-unrolled loop,
// all static indexing). The exp VALU stream is then independent of the
// in-flight QK MFMAs -> compiler interleaves it into the MFMA shadow.
// QBLK=128 (R1's proven A/B fragments), KVBLK=64 (R7's verified staging),
// 3 LDS tile buffers (t-1,t,t+1 live; 48KB), 1 barrier/tile, stage(t+1)
// right after the barrier (R7 cadence). Grid (16,32)=512 = 2 blocks/CU.
// XCD swizzle kept (FETCH 12MB). Maxless softmax, denom via MFMA vs ones.
__global__ __launch_bounds__(256, 2) void attn_kernel(const u16* __restrict__ qb,
                                                      const u16* __restrict__ kb,
                                                      const u16* __restrict__ vT,
                                                      u16* __restrict__ att_out) {
    __shared__ __align__(16) u16 smem[3 * 8192];   // 3 bufs: [Ks 64*64 | Vs 64*64]
    const int tid = threadIdx.x;
    const int wave = tid >> 6, lane = tid & 63;
    const int quad = lane >> 4, l16 = lane & 15;
    const int lin = blockIdx.y * 16 + blockIdx.x;          // 0..511
    const int nlin = (lin & 7) * 64 + (lin >> 3);          // bijective (512%8==0)
    const int qt = nlin & 15, bh = nlin >> 4;
    const int b = bh >> 4, h = bh & 15;

    // 32 q rows per wave (A: rows wave*32+0..15, B: +16), pre-scaled q
    const u16* qrowA = &qb[(size_t)(bh * 2048 + qt * 128 + wave * 32 + l16) * 64];
    const bf16x8 qA0 = *(const bf16x8*)&qrowA[quad * 8];
    const bf16x8 qA1 = *(const bf16x8*)&qrowA[32 + quad * 8];
    const u16* qrowB = qrowA + 16 * 64;
    const bf16x8 qB0 = *(const bf16x8*)&qrowB[quad * 8];
    const bf16x8 qB1 = *(const bf16x8*)&qrowB[32 + quad * 8];

    // staging (KVBLK=64): 2 K chunks + 2 V chunks per wave (R7-verified)
    const u16* ksrc[2];
    const u16* vsrc[2];
    int kofs[2], vofs[2];
    #pragma unroll
    for (int j = 0; j < 2; ++j) {
        const int p = 8 * wave + 32 * j + (lane >> 3);      // 0..63
        const int kr = (p & 0x60) | ((p & 12) << 1) | ((p & 16) >> 2) | (p & 3);
        const int gk = (lane & 7) ^ (p & 7);
        ksrc[j] = kb + ((size_t)bh * 2048 + kr) * 64 + gk * 8;
        kofs[j] = (8 * wave + 32 * j) * 64;
        const int d = 8 * wave + 32 * j + (lane >> 3);      // 0..63
        const int gv = (lane & 7) ^ ((d >> 1) & 7);
        vsrc[j] = vT + ((size_t)bh * 64 + d) * 2048 + gv * 8;
        vofs[j] = 4096 + (8 * wave + 32 * j) * 64;
    }

    f32x4 oA[4] = {}, oB[4] = {};
    f32x4 lA = {}, lB = {};
    f32x4 s0A[4], s0B[4], s1A[4], s1B[4];
    bf16x8 ones;
    #pragma unroll
    for (int i = 0; i < 8; ++i) ones[i] = (__bf16)1.0f;

    auto stage = [&](int buf) {
        u16* dst = smem + buf * 8192;
        #pragma unroll
        for (int j = 0; j < 2; ++j) {
            gload_lds16(ksrc[j], dst + kofs[j]);
            gload_lds16(vsrc[j], dst + vofs[j]);
            ksrc[j] += 64 * 64;
            vsrc[j] += 64;
        }
    };
    auto QK = [&](int buf, f32x4 (&sA)[4], f32x4 (&sB)[4]) {
        const u16* Ks = smem + buf * 8192;
        #pragma unroll
        for (int nt = 0; nt < 4; ++nt) {
            const int r = nt * 16 + l16;
            const bf16x8 k0 = *(const bf16x8*)&Ks[r * 64 + (((quad) ^ (r & 7)) << 3)];
            const bf16x8 k1 = *(const bf16x8*)&Ks[r * 64 + (((quad + 4) ^ (r & 7)) << 3)];
            f32x4 a = {}, c = {};
            a = __builtin_amdgcn_mfma_f32_16x16x32_bf16(k0, qA0, a, 0, 0, 0);
            a = __builtin_amdgcn_mfma_f32_16x16x32_bf16(k1, qA1, a, 0, 0, 0);
            c = __builtin_amdgcn_mfma_f32_16x16x32_bf16(k0, qB0, c, 0, 0, 0);
            c = __builtin_amdgcn_mfma_f32_16x16x32_bf16(k1, qB1, c, 0, 0, 0);
            sA[nt] = a;
            sB[nt] = c;
        }
    };
    auto EXPPV = [&](int buf, f32x4 (&sA)[4], f32x4 (&sB)[4]) {
        bf16x8 apA[2], apB[2];
        #pragma unroll
        for (int nt = 0; nt < 4; ++nt)
            #pragma unroll
            for (int e = 0; e < 4; ++e) {
                apA[nt >> 1][(nt & 1) * 4 + e] = (__bf16)__builtin_amdgcn_exp2f(sA[nt][e]);
                apB[nt >> 1][(nt & 1) * 4 + e] = (__bf16)__builtin_amdgcn_exp2f(sB[nt][e]);
            }
        const u16* Vs = smem + buf * 8192 + 4096;
        #pragma unroll
        for (int vt = 0; vt < 4; ++vt) {
            const int dd = vt * 16 + l16;
            #pragma unroll
            for (int c = 0; c < 2; ++c) {
                const bf16x8 vf = *(const bf16x8*)&Vs[dd * 64 + (((c * 4 + quad) ^ ((dd >> 1) & 7)) << 3)];
                oA[vt] = __builtin_amdgcn_mfma_f32_16x16x32_bf16(apA[c], vf, oA[vt], 0, 0, 0);
                oB[vt] = __builtin_amdgcn_mfma_f32_16x16x32_bf16(apB[c], vf, oB[vt], 0, 0, 0);
            }
        }
        #pragma unroll
        for (int c = 0; c < 2; ++c) {
            lA = __builtin_amdgcn_mfma_f32_16x16x32_bf16(apA[c], ones, lA, 0, 0, 0);
            lB = __builtin_amdgcn_mfma_f32_16x16x32_bf16(apB[c], ones, lB, 0, 0, 0);
        }
    };

    // prologue: tiles 0,1 staged; QK(0)
    stage(0);
    stage(1);
    __syncthreads();                     // drains both stages block-wide
    QK(0, s0A, s0B);

    int bPrev = 0, bCur = 1, bNext = 2;  // buffers of tiles t-1, t, t+1
    #pragma unroll 1
    for (int tp = 0; tp < 15; ++tp) {
        // ---- odd tile t = 2tp+1
        __syncthreads();                 // tile t staged; all reads of tile t-2 done
        stage(bNext);                    // tile t+1 into freed buffer
        __builtin_amdgcn_s_setprio(1);
        QK(bCur, s1A, s1B);              // MFMA stream (tile t)
        EXPPV(bPrev, s0A, s0B);          // independent VALU+MFMA (tile t-1)
        __builtin_amdgcn_s_setprio(0);
        bPrev = bCur; bCur = bNext; bNext = (bNext == 2) ? 0 : bNext + 1;
        // ---- even tile t = 2tp+2
        __syncthreads();
        stage(bNext);                    // tile t+1 (tp=14 stages tile 31)
        __builtin_amdgcn_s_setprio(1);
        QK(bCur, s0A, s0B);
        EXPPV(bPrev, s1A, s1B);
        __builtin_amdgcn_s_setprio(0);
        bPrev = bCur; bCur = bNext; bNext = (bNext == 2) ? 0 : bNext + 1;
    }
    // tail: t = 31 (QK) + finish tiles 30, 31
    __syncthreads();
    __builtin_amdgcn_s_setprio(1);
    QK(bCur, s1A, s1B);                  // tile 31
    EXPPV(bPrev, s0A, s0B);              // tile 30
    EXPPV(bCur, s1A, s1B);               // tile 31
    __builtin_amdgcn_s_setprio(0);

    #pragma unroll
    for (int e = 0; e < 4; ++e) {
        const float invA = 1.0f / lA[e];
        const float invB = 1.0f / lB[e];
        const int nA = qt * 128 + wave * 32 + quad * 4 + e;
        #pragma unroll
        for (int vt = 0; vt < 4; ++vt) {
            att_out[(size_t)(b * 2048 + nA) * 1024 + h * 64 + vt * 16 + l16] = f2bf(oA[vt][e] * invA);
            att_out[(size_t)(b * 2048 + nA + 16) * 1024 + h * 64 + vt * 16 + l16] = f2bf(oB[vt][e] * invB);
        }
    }
}

// ---- GEMM2 (R19 128x128) + R20 XCD swizzle: each XCD owns 1 B-panel ----
__global__ __launch_bounds__(256, 3) void gemm_proj(const u16* __restrict__ A,
                                                    const u16* __restrict__ Bt,
                                                    const float* __restrict__ bias,
                                                    const float* __restrict__ z,
                                                    float* __restrict__ out) {
    __shared__ __align__(16) u16 sm[2 * 4096];
    u16* const As = sm;                           // 128*32
    u16* const Bs = sm + 4096;                    // 128*32
    const int tid = threadIdx.x;
    const int wave = tid >> 6, lane = tid & 63;
    const int quad = lane >> 4, l16 = lane & 15;
    const int wm = (wave >> 1) * 64, wn = (wave & 1) * 64;
    const int lin = blockIdx.y * 32 + blockIdx.x;          // 0..255
    const int nlin = (lin & 7) * 32 + (lin >> 3);          // bijective (256%8==0)
    const int bxs = nlin & 31, bys = nlin >> 5;
    const int row0 = bxs * 128, col0 = bys * 128;
    const int gr = lane >> 2, gc = (lane & 3) * 8;
    f32x4 acc[4][4] = {};
    for (int kt = 0; kt < 1024; kt += 32) {
        __syncthreads();
        #pragma unroll
        for (int i = 0; i < 2; ++i) {
            const int rb = wave * 16 + i * 64;
            gload_lds16(&A[(size_t)(row0 + rb + gr) * 1024 + kt + gc], &As[rb * 32]);
            gload_lds16(&Bt[(size_t)(col0 + rb + gr) * 1024 + kt + gc], &Bs[rb * 32]);
        }
        __syncthreads();
        bf16x8 ax[4], bx[4];
        #pragma unroll
        for (int t = 0; t < 4; ++t) {
            ax[t] = *(const bf16x8*)&As[(wm + t * 16 + l16) * 32 + quad * 8];
            bx[t] = *(const bf16x8*)&Bs[(wn + t * 16 + l16) * 32 + quad * 8];
        }
        #pragma unroll
        for (int mt = 0; mt < 4; ++mt)
            #pragma unroll
            for (int nt = 0; nt < 4; ++nt)
                acc[mt][nt] = __builtin_amdgcn_mfma_f32_16x16x32_bf16(ax[mt], bx[nt], acc[mt][nt], 0, 0, 0);
    }
    #pragma unroll
    for (int mt = 0; mt < 4; ++mt) {
        #pragma unroll
        for (int nt = 0; nt < 4; ++nt) {
            #pragma unroll
            for (int e = 0; e < 4; ++e) {
                const int row = row0 + wm + mt * 16 + quad * 4 + e;
                const int col = col0 + wn + nt * 16 + l16;
                out[(size_t)row * 1024 + col] = acc[mt][nt][e] + bias[col] + z[(size_t)row * 1024 + col];
            }
        }
    }
}

extern "C" void kernel_launch(void* const* d_in, const int* in_sizes, int n_in,
                              void* d_out, int out_size, void* d_ws, size_t ws_size,
                              hipStream_t stream) {
    const float* z        = (const float*)d_in[0];
    const float* ln_scale = (const float*)d_in[1];
    const float* ln_bias  = (const float*)d_in[2];
    const float* w_qkv    = (const float*)d_in[3];
    const float* w_proj   = (const float*)d_in[4];
    const float* b_proj   = (const float*)d_in[5];
    float* out = (float*)d_out;

    char* ws = (char*)d_ws;
    u16* zn     = (u16*)(ws);                       // 0-8 MiB   [4096,1024]
    u16* wqkvT  = (u16*)(ws + (8u << 20));          // 8-14 MiB  [3072,1024] (rows permuted)
    u16* wprojT = (u16*)(ws + (14u << 20));         // 14-16 MiB [1024,1024]
    u16* qbuf   = (u16*)(ws + (16u << 20));         // 16-24 MiB [32,2048,64] (pre-scaled 0.125*log2e)
    u16* kbuf   = (u16*)(ws + (24u << 20));         // 24-32 MiB [32,2048,64]
    u16* vT     = (u16*)(ws + (32u << 20));         // 32-40 MiB [32,64,2048] (written by gemm_qkv)
    u16* att_o  = (u16*)(ws + (40u << 20));         // 40-48 MiB [4096,1024]

    prep_kernel<<<dim3(4096 + 1536 + 512), 256, 0, stream>>>(
        z, ln_scale, ln_bias, w_qkv, w_proj, zn, wqkvT, wprojT);
    gemm_qkv<<<dim3(32, 24), 256, 0, stream>>>(zn, wqkvT, qbuf, kbuf, vT);
    attn_kernel<<<dim3(16, 32), 256, 0, stream>>>(qbuf, kbuf, vT, att_o);
    gemm_proj<<<dim3(32, 8), 256, 0, stream>>>(att_o, wprojT, b_proj, z, out);
}

// Round 9
// 173.298 us; speedup vs baseline: 1.0536x; 1.0376x over previous
//
#include <hip/hip_runtime.h>
#include <stdint.h>
#include <math.h>

typedef unsigned short u16;
typedef float f32x4 __attribute__((ext_vector_type(4)));
typedef __bf16 bf16x8 __attribute__((ext_vector_type(8)));

__device__ __forceinline__ u16 f2bf(float f) {
    union { float f; uint32_t u; } c; c.f = f;
    return (u16)((c.u + 0x7FFFu + ((c.u >> 16) & 1u)) >> 16);
}

__device__ __forceinline__ void gload_lds16(const void* g, void* l) {
    __builtin_amdgcn_global_load_lds(
        (const __attribute__((address_space(1))) unsigned int*)g,
        (__attribute__((address_space(3))) unsigned int*)l, 16, 0, 0);
}

// --------- fused prep: LN (blocks 0..1023, 4 rows/block wave-per-row) +
// --------- w_qkv transpose (next 1536) + w_proj transpose (last 512).
// R24: LN is now one wave per row — pure shfl_xor reduction, no barriers,
// no LDS (old: 4096 blocks, 2 barriers + LDS roundtrip per row).
__global__ __launch_bounds__(256) void prep_kernel(const float* __restrict__ z,
                                                   const float* __restrict__ sc,
                                                   const float* __restrict__ bs,
                                                   const float* __restrict__ w_qkv,
                                                   const float* __restrict__ w_proj,
                                                   u16* __restrict__ zn,
                                                   u16* __restrict__ wqkvT,
                                                   u16* __restrict__ wprojT) {
    __shared__ __align__(16) float t[32][68];
    const int tid = threadIdx.x;
    const int bid = blockIdx.x;

    if (bid < 1024) {                      // ---- LayerNorm: wave w owns row bid*4+w
        const int wave = tid >> 6, lane = tid & 63;
        const int row = bid * 4 + wave;
        const float* zr = z + (size_t)row * 1024;
        float4 v[4], scv[4], bsv[4];
        #pragma unroll
        for (int i = 0; i < 4; ++i) v[i] = ((const float4*)zr)[i * 64 + lane];
        float s = 0.0f;
        #pragma unroll
        for (int i = 0; i < 4; ++i) s += v[i].x + v[i].y + v[i].z + v[i].w;
        #pragma unroll
        for (int off = 32; off > 0; off >>= 1) s += __shfl_xor(s, off);
        const float mean = s * (1.0f / 1024.0f);
        float q = 0.0f;
        #pragma unroll
        for (int i = 0; i < 4; ++i) {
            const float dx = v[i].x - mean, dy = v[i].y - mean;
            const float dz = v[i].z - mean, dw = v[i].w - mean;
            q += dx * dx + dy * dy + dz * dz + dw * dw;
        }
        #pragma unroll
        for (int off = 32; off > 0; off >>= 1) q += __shfl_xor(q, off);
        const float var = q * (1.0f / 1024.0f);
        const float rstd = rsqrtf(var + 1e-5f);
        #pragma unroll
        for (int i = 0; i < 4; ++i) {
            scv[i] = ((const float4*)sc)[i * 64 + lane];
            bsv[i] = ((const float4*)bs)[i * 64 + lane];
        }
        #pragma unroll
        for (int i = 0; i < 4; ++i) {
            const u16 o0 = f2bf((v[i].x - mean) * rstd * scv[i].x + bsv[i].x);
            const u16 o1 = f2bf((v[i].y - mean) * rstd * scv[i].y + bsv[i].y);
            const u16 o2 = f2bf((v[i].z - mean) * rstd * scv[i].z + bsv[i].z);
            const u16 o3 = f2bf((v[i].w - mean) * rstd * scv[i].w + bsv[i].w);
            uint2 pk;
            pk.x = (uint32_t)o0 | ((uint32_t)o1 << 16);
            pk.y = (uint32_t)o2 | ((uint32_t)o3 << 16);
            *(uint2*)&zn[(size_t)row * 1024 + (i * 64 + lane) * 4] = pk;
        }
        return;
    }

    const float* in;
    u16* out;
    int N, permute, bx, by;
    if (bid < 1024 + 1536) {               // w_qkv: [1024,3072] -> permuted [3072,1024]
        const int r = bid - 1024;
        in = w_qkv; out = wqkvT; N = 3072; permute = 1;
        bx = r % 48; by = r / 48;
    } else {                               // w_proj: [1024,1024] -> [1024,1024]
        const int r = bid - 1024 - 1536;
        in = w_proj; out = wprojT; N = 1024; permute = 0;
        bx = r % 16; by = r / 16;
    }
    const int kb = by * 32, nb = bx * 64;
    const int lr = tid >> 3, lq = tid & 7;
    const float* src = &in[(size_t)(kb + lr) * N + nb + lq * 8];
    const float4 va = *(const float4*)src;
    const float4 vb = *(const float4*)(src + 4);
    *(float4*)&t[lr][lq * 8] = va;
    *(float4*)&t[lr][lq * 8 + 4] = vb;
    __syncthreads();
    const int cj = tid >> 6, c = tid & 63;
    const int col = nb + c;
    int np = col;
    if (permute) {
        const int h = col / 192, rem = col - h * 192;
        const int d = rem / 3, s = rem - d * 3;
        np = s * 1024 + h * 64 + d;
    }
    u16 pk[8];
    #pragma unroll
    for (int u = 0; u < 8; ++u) pk[u] = f2bf(t[cj * 8 + u][c]);
    *(uint4*)&out[(size_t)np * 1024 + kb + cj * 8] = *(const uint4*)pk;
}

// ---------------- GEMM1 — R24: BK=64 (half the barrier drains) -------------
// 128-B LDS rows would be 16-way bank-conflicted; fixed with the attn-proven
// pre-swizzled-source pattern: stage global chunk gc8^gr8 into linear LDS
// chunk gc8 (gload_lds writes lane-linear, rule #21), read chunk
// (kk*4+quad)^(l16&7) — XORs cancel, lanes spread 8 bank-groups x2 = free.
// ax/bx reused across the two kk sub-steps -> register peak unchanged.
__global__ __launch_bounds__(256, 3) void gemm_qkv(const u16* __restrict__ A,
                                                   const u16* __restrict__ Bt,
                                                   u16* __restrict__ qbuf,
                                                   u16* __restrict__ kbuf,
                                                   u16* __restrict__ vT) {
    __shared__ __align__(16) u16 sm[16384];      // As 128*64 | Bs 128*64 (32 KB)
    u16* const As = sm;
    u16* const Bs = sm + 8192;
    const int tid = threadIdx.x;
    const int wave = tid >> 6, lane = tid & 63;
    const int quad = lane >> 4, l16 = lane & 15;
    const int wm = (wave >> 1) * 64, wn = (wave & 1) * 64;
    const int lin = blockIdx.y * 32 + blockIdx.x;           // 0..767
    const int nlin = (lin & 7) * 96 + (lin >> 3);           // bijective (768%8==0)
    const int bxs = nlin & 31, bys = nlin >> 5;
    const int row0 = bxs * 128, col0 = bys * 128;
    const int gr8 = lane >> 3, gc8 = lane & 7;
    const int sca = (gc8 ^ gr8) * 8;             // pre-swizzled source column
    f32x4 acc[4][4] = {};
    for (int kt = 0; kt < 1024; kt += 64) {
        __syncthreads();
        #pragma unroll
        for (int j = 0; j < 4; ++j) {
            const int rb = wave * 8 + j * 32;
            gload_lds16(&A[(size_t)(row0 + rb + gr8) * 1024 + kt + sca], &As[rb * 64]);
            gload_lds16(&Bt[(size_t)(col0 + rb + gr8) * 1024 + kt + sca], &Bs[rb * 64]);
        }
        __syncthreads();
        #pragma unroll
        for (int kk = 0; kk < 2; ++kk) {
            bf16x8 ax[4], bx[4];
            #pragma unroll
            for (int t = 0; t < 4; ++t) {
                const int ar = wm + t * 16 + l16;
                ax[t] = *(const bf16x8*)&As[ar * 64 + (((kk * 4 + quad) ^ (l16 & 7)) << 3)];
                const int br = wn + t * 16 + l16;
                bx[t] = *(const bf16x8*)&Bs[br * 64 + (((kk * 4 + quad) ^ (l16 & 7)) << 3)];
            }
            #pragma unroll
            for (int mt = 0; mt < 4; ++mt)
                #pragma unroll
                for (int nt = 0; nt < 4; ++nt)
                    acc[mt][nt] = __builtin_amdgcn_mfma_f32_16x16x32_bf16(ax[mt], bx[nt], acc[mt][nt], 0, 0, 0);
        }
    }
    const int s = col0 >> 10;                 // block-uniform
    if (s < 2) {
        u16* const dst = (s == 0) ? qbuf : kbuf;
        const float scl = (s == 0) ? 0.125f * 1.44269504088896f : 1.0f;
        #pragma unroll
        for (int mt = 0; mt < 4; ++mt) {
            #pragma unroll
            for (int nt = 0; nt < 4; ++nt) {
                #pragma unroll
                for (int e = 0; e < 4; ++e) {
                    const int row = row0 + wm + mt * 16 + quad * 4 + e;
                    const int col = col0 + wn + nt * 16 + l16;
                    const int b = row >> 11, n = row & 2047;
                    const int h = (col >> 6) & 15, d = col & 63;
                    dst[((size_t)(b * 16 + h) * 2048 + n) * 64 + d] = f2bf(acc[mt][nt][e] * scl);
                }
            }
        }
    } else {
        // V: transpose 128x128 tile through LDS, store to vT[bh,d,n].
        const int b = row0 >> 11, n0 = row0 & 2047;
        const int h0 = (col0 >> 6) & 15;          // col0 = 2048 + cb*128 -> h0 = 2*cb
        for (int hh = 0; hh < 2; ++hh) {
            __syncthreads();                      // tile buffer free (main loop / prev pass done)
            if ((wave & 1) == hh) {               // wn == hh*64 waves own this col-half
                #pragma unroll
                for (int mt = 0; mt < 4; ++mt) {
                    const int rl = wm + mt * 16 + quad * 4;       // multiple of 4 -> 8B aligned
                    #pragma unroll
                    for (int nt = 0; nt < 4; ++nt) {
                        const int cl = nt * 16 + l16;             // d 0..63
                        u16 tmp[4];
                        #pragma unroll
                        for (int e = 0; e < 4; ++e) tmp[e] = f2bf(acc[mt][nt][e]);
                        *(uint2*)&sm[cl * 136 + rl] = *(const uint2*)tmp;   // ds_write_b64
                    }
                }
            }
            __syncthreads();
            const int bh = b * 16 + h0 + hh;
            #pragma unroll
            for (int pass = 0; pass < 4; ++pass) {
                const int chunk = pass * 256 + tid;   // 0..1023
                const int d = chunk >> 4;             // 0..63
                const int nc = chunk & 15;            // 16 chunks of 8 n
                const uint4 vv = *(const uint4*)&sm[d * 136 + nc * 8];
                *(uint4*)&vT[((size_t)bh * 64 + d) * 2048 + n0 + nc * 8] = vv;
            }
        }
    }
}

// -------- Fused flash attention (R23 2-deep S-pipeline, kept) --------------
// Measured 41.8us = ~823 TF-equiv = 91% of the best documented plain-HIP
// attn (~900 TF, m214). MFMA floor ~16us + TRANS/VALU ~15us do not overlap
// intra-wave on this toolchain (m253-documented null); 5 structures all
// land 42-46us. Kept as-is.
__global__ __launch_bounds__(256, 2) void attn_kernel(const u16* __restrict__ qb,
                                                      const u16* __restrict__ kb,
                                                      const u16* __restrict__ vT,
                                                      u16* __restrict__ att_out) {
    __shared__ __align__(16) u16 smem[3 * 8192];   // 3 bufs: [Ks 64*64 | Vs 64*64]
    const int tid = threadIdx.x;
    const int wave = tid >> 6, lane = tid & 63;
    const int quad = lane >> 4, l16 = lane & 15;
    const int lin = blockIdx.y * 16 + blockIdx.x;          // 0..511
    const int nlin = (lin & 7) * 64 + (lin >> 3);          // bijective (512%8==0)
    const int qt = nlin & 15, bh = nlin >> 4;
    const int b = bh >> 4, h = bh & 15;

    const u16* qrowA = &qb[(size_t)(bh * 2048 + qt * 128 + wave * 32 + l16) * 64];
    const bf16x8 qA0 = *(const bf16x8*)&qrowA[quad * 8];
    const bf16x8 qA1 = *(const bf16x8*)&qrowA[32 + quad * 8];
    const u16* qrowB = qrowA + 16 * 64;
    const bf16x8 qB0 = *(const bf16x8*)&qrowB[quad * 8];
    const bf16x8 qB1 = *(const bf16x8*)&qrowB[32 + quad * 8];

    const u16* ksrc[2];
    const u16* vsrc[2];
    int kofs[2], vofs[2];
    #pragma unroll
    for (int j = 0; j < 2; ++j) {
        const int p = 8 * wave + 32 * j + (lane >> 3);      // 0..63
        const int kr = (p & 0x60) | ((p & 12) << 1) | ((p & 16) >> 2) | (p & 3);
        const int gk = (lane & 7) ^ (p & 7);
        ksrc[j] = kb + ((size_t)bh * 2048 + kr) * 64 + gk * 8;
        kofs[j] = (8 * wave + 32 * j) * 64;
        const int d = 8 * wave + 32 * j + (lane >> 3);      // 0..63
        const int gv = (lane & 7) ^ ((d >> 1) & 7);
        vsrc[j] = vT + ((size_t)bh * 64 + d) * 2048 + gv * 8;
        vofs[j] = 4096 + (8 * wave + 32 * j) * 64;
    }

    f32x4 oA[4] = {}, oB[4] = {};
    f32x4 lA = {}, lB = {};
    f32x4 s0A[4], s0B[4], s1A[4], s1B[4];
    bf16x8 ones;
    #pragma unroll
    for (int i = 0; i < 8; ++i) ones[i] = (__bf16)1.0f;

    auto stage = [&](int buf) {
        u16* dst = smem + buf * 8192;
        #pragma unroll
        for (int j = 0; j < 2; ++j) {
            gload_lds16(ksrc[j], dst + kofs[j]);
            gload_lds16(vsrc[j], dst + vofs[j]);
            ksrc[j] += 64 * 64;
            vsrc[j] += 64;
        }
    };
    auto QK = [&](int buf, f32x4 (&sA)[4], f32x4 (&sB)[4]) {
        const u16* Ks = smem + buf * 8192;
        #pragma unroll
        for (int nt = 0; nt < 4; ++nt) {
            const int r = nt * 16 + l16;
            const bf16x8 k0 = *(const bf16x8*)&Ks[r * 64 + (((quad) ^ (r & 7)) << 3)];
            const bf16x8 k1 = *(const bf16x8*)&Ks[r * 64 + (((quad + 4) ^ (r & 7)) << 3)];
            f32x4 a = {}, c = {};
            a = __builtin_amdgcn_mfma_f32_16x16x32_bf16(k0, qA0, a, 0, 0, 0);
            a = __builtin_amdgcn_mfma_f32_16x16x32_bf16(k1, qA1, a, 0, 0, 0);
            c = __builtin_amdgcn_mfma_f32_16x16x32_bf16(k0, qB0, c, 0, 0, 0);
            c = __builtin_amdgcn_mfma_f32_16x16x32_bf16(k1, qB1, c, 0, 0, 0);
            sA[nt] = a;
            sB[nt] = c;
        }
    };
    auto EXPPV = [&](int buf, f32x4 (&sA)[4], f32x4 (&sB)[4]) {
        bf16x8 apA[2], apB[2];
        #pragma unroll
        for (int nt = 0; nt < 4; ++nt)
            #pragma unroll
            for (int e = 0; e < 4; ++e) {
                apA[nt >> 1][(nt & 1) * 4 + e] = (__bf16)__builtin_amdgcn_exp2f(sA[nt][e]);
                apB[nt >> 1][(nt & 1) * 4 + e] = (__bf16)__builtin_amdgcn_exp2f(sB[nt][e]);
            }
        const u16* Vs = smem + buf * 8192 + 4096;
        #pragma unroll
        for (int vt = 0; vt < 4; ++vt) {
            const int dd = vt * 16 + l16;
            #pragma unroll
            for (int c = 0; c < 2; ++c) {
                const bf16x8 vf = *(const bf16x8*)&Vs[dd * 64 + (((c * 4 + quad) ^ ((dd >> 1) & 7)) << 3)];
                oA[vt] = __builtin_amdgcn_mfma_f32_16x16x32_bf16(apA[c], vf, oA[vt], 0, 0, 0);
                oB[vt] = __builtin_amdgcn_mfma_f32_16x16x32_bf16(apB[c], vf, oB[vt], 0, 0, 0);
            }
        }
        #pragma unroll
        for (int c = 0; c < 2; ++c) {
            lA = __builtin_amdgcn_mfma_f32_16x16x32_bf16(apA[c], ones, lA, 0, 0, 0);
            lB = __builtin_amdgcn_mfma_f32_16x16x32_bf16(apB[c], ones, lB, 0, 0, 0);
        }
    };

    stage(0);
    stage(1);
    __syncthreads();
    QK(0, s0A, s0B);

    int bPrev = 0, bCur = 1, bNext = 2;
    #pragma unroll 1
    for (int tp = 0; tp < 15; ++tp) {
        __syncthreads();
        stage(bNext);
        __builtin_amdgcn_s_setprio(1);
        QK(bCur, s1A, s1B);
        EXPPV(bPrev, s0A, s0B);
        __builtin_amdgcn_s_setprio(0);
        bPrev = bCur; bCur = bNext; bNext = (bNext == 2) ? 0 : bNext + 1;
        __syncthreads();
        stage(bNext);
        __builtin_amdgcn_s_setprio(1);
        QK(bCur, s0A, s0B);
        EXPPV(bPrev, s1A, s1B);
        __builtin_amdgcn_s_setprio(0);
        bPrev = bCur; bCur = bNext; bNext = (bNext == 2) ? 0 : bNext + 1;
    }
    __syncthreads();
    __builtin_amdgcn_s_setprio(1);
    QK(bCur, s1A, s1B);
    EXPPV(bPrev, s0A, s0B);
    EXPPV(bCur, s1A, s1B);
    __builtin_amdgcn_s_setprio(0);

    #pragma unroll
    for (int e = 0; e < 4; ++e) {
        const float invA = 1.0f / lA[e];
        const float invB = 1.0f / lB[e];
        const int nA = qt * 128 + wave * 32 + quad * 4 + e;
        #pragma unroll
        for (int vt = 0; vt < 4; ++vt) {
            att_out[(size_t)(b * 2048 + nA) * 1024 + h * 64 + vt * 16 + l16] = f2bf(oA[vt][e] * invA);
            att_out[(size_t)(b * 2048 + nA + 16) * 1024 + h * 64 + vt * 16 + l16] = f2bf(oB[vt][e] * invB);
        }
    }
}

// ---- GEMM2 (R19 128x128) + R20 XCD swizzle: each XCD owns 1 B-panel ----
__global__ __launch_bounds__(256, 3) void gemm_proj(const u16* __restrict__ A,
                                                    const u16* __restrict__ Bt,
                                                    const float* __restrict__ bias,
                                                    const float* __restrict__ z,
                                                    float* __restrict__ out) {
    __shared__ __align__(16) u16 sm[2 * 4096];
    u16* const As = sm;                           // 128*32
    u16* const Bs = sm + 4096;                    // 128*32
    const int tid = threadIdx.x;
    const int wave = tid >> 6, lane = tid & 63;
    const int quad = lane >> 4, l16 = lane & 15;
    const int wm = (wave >> 1) * 64, wn = (wave & 1) * 64;
    const int lin = blockIdx.y * 32 + blockIdx.x;          // 0..255
    const int nlin = (lin & 7) * 32 + (lin >> 3);          // bijective (256%8==0)
    const int bxs = nlin & 31, bys = nlin >> 5;
    const int row0 = bxs * 128, col0 = bys * 128;
    const int gr = lane >> 2, gc = (lane & 3) * 8;
    f32x4 acc[4][4] = {};
    for (int kt = 0; kt < 1024; kt += 32) {
        __syncthreads();
        #pragma unroll
        for (int i = 0; i < 2; ++i) {
            const int rb = wave * 16 + i * 64;
            gload_lds16(&A[(size_t)(row0 + rb + gr) * 1024 + kt + gc], &As[rb * 32]);
            gload_lds16(&Bt[(size_t)(col0 + rb + gr) * 1024 + kt + gc], &Bs[rb * 32]);
        }
        __syncthreads();
        bf16x8 ax[4], bx[4];
        #pragma unroll
        for (int t = 0; t < 4; ++t) {
            ax[t] = *(const bf16x8*)&As[(wm + t * 16 + l16) * 32 + quad * 8];
            bx[t] = *(const bf16x8*)&Bs[(wn + t * 16 + l16) * 32 + quad * 8];
        }
        #pragma unroll
        for (int mt = 0; mt < 4; ++mt)
            #pragma unroll
            for (int nt = 0; nt < 4; ++nt)
                acc[mt][nt] = __builtin_amdgcn_mfma_f32_16x16x32_bf16(ax[mt], bx[nt], acc[mt][nt], 0, 0, 0);
    }
    #pragma unroll
    for (int mt = 0; mt < 4; ++mt) {
        #pragma unroll
        for (int nt = 0; nt < 4; ++nt) {
            #pragma unroll
            for (int e = 0; e < 4; ++e) {
                const int row = row0 + wm + mt * 16 + quad * 4 + e;
                const int col = col0 + wn + nt * 16 + l16;
                out[(size_t)row * 1024 + col] = acc[mt][nt][e] + bias[col] + z[(size_t)row * 1024 + col];
            }
        }
    }
}

extern "C" void kernel_launch(void* const* d_in, const int* in_sizes, int n_in,
                              void* d_out, int out_size, void* d_ws, size_t ws_size,
                              hipStream_t stream) {
    const float* z        = (const float*)d_in[0];
    const float* ln_scale = (const float*)d_in[1];
    const float* ln_bias  = (const float*)d_in[2];
    const float* w_qkv    = (const float*)d_in[3];
    const float* w_proj   = (const float*)d_in[4];
    const float* b_proj   = (const float*)d_in[5];
    float* out = (float*)d_out;

    char* ws = (char*)d_ws;
    u16* zn     = (u16*)(ws);                       // 0-8 MiB   [4096,1024]
    u16* wqkvT  = (u16*)(ws + (8u << 20));          // 8-14 MiB  [3072,1024] (rows permuted)
    u16* wprojT = (u16*)(ws + (14u << 20));         // 14-16 MiB [1024,1024]
    u16* qbuf   = (u16*)(ws + (16u << 20));         // 16-24 MiB [32,2048,64] (pre-scaled 0.125*log2e)
    u16* kbuf   = (u16*)(ws + (24u << 20));         // 24-32 MiB [32,2048,64]
    u16* vT     = (u16*)(ws + (32u << 20));         // 32-40 MiB [32,64,2048] (written by gemm_qkv)
    u16* att_o  = (u16*)(ws + (40u << 20));         // 40-48 MiB [4096,1024]

    prep_kernel<<<dim3(1024 + 1536 + 512), 256, 0, stream>>>(
        z, ln_scale, ln_bias, w_qkv, w_proj, zn, wqkvT, wprojT);
    gemm_qkv<<<dim3(32, 24), 256, 0, stream>>>(zn, wqkvT, qbuf, kbuf, vT);
    attn_kernel<<<dim3(16, 32), 256, 0, stream>>>(qbuf, kbuf, vT, att_o);
    gemm_proj<<<dim3(32, 8), 256, 0, stream>>>(att_o, wprojT, b_proj, z, out);
}

// Round 10
// 172.364 us; speedup vs baseline: 1.0593x; 1.0054x over previous
//
#include <hip/hip_runtime.h>
#include <stdint.h>
#include <math.h>

typedef unsigned short u16;
typedef float f32x4 __attribute__((ext_vector_type(4)));
typedef __bf16 bf16x8 __attribute__((ext_vector_type(8)));

__device__ __forceinline__ u16 f2bf(float f) {
    union { float f; uint32_t u; } c; c.f = f;
    return (u16)((c.u + 0x7FFFu + ((c.u >> 16) & 1u)) >> 16);
}

__device__ __forceinline__ void gload_lds16(const void* g, void* l) {
    __builtin_amdgcn_global_load_lds(
        (const __attribute__((address_space(1))) unsigned int*)g,
        (__attribute__((address_space(3))) unsigned int*)l, 16, 0, 0);
}

// --------- fused prep: LN (blocks 0..1023, 4 rows/block wave-per-row) +
// --------- w_qkv transpose (next 1536) + w_proj transpose (last 512).
__global__ __launch_bounds__(256) void prep_kernel(const float* __restrict__ z,
                                                   const float* __restrict__ sc,
                                                   const float* __restrict__ bs,
                                                   const float* __restrict__ w_qkv,
                                                   const float* __restrict__ w_proj,
                                                   u16* __restrict__ zn,
                                                   u16* __restrict__ wqkvT,
                                                   u16* __restrict__ wprojT) {
    __shared__ __align__(16) float t[32][68];
    const int tid = threadIdx.x;
    const int bid = blockIdx.x;

    if (bid < 1024) {                      // ---- LayerNorm: wave w owns row bid*4+w
        const int wave = tid >> 6, lane = tid & 63;
        const int row = bid * 4 + wave;
        const float* zr = z + (size_t)row * 1024;
        float4 v[4], scv[4], bsv[4];
        #pragma unroll
        for (int i = 0; i < 4; ++i) v[i] = ((const float4*)zr)[i * 64 + lane];
        float s = 0.0f;
        #pragma unroll
        for (int i = 0; i < 4; ++i) s += v[i].x + v[i].y + v[i].z + v[i].w;
        #pragma unroll
        for (int off = 32; off > 0; off >>= 1) s += __shfl_xor(s, off);
        const float mean = s * (1.0f / 1024.0f);
        float q = 0.0f;
        #pragma unroll
        for (int i = 0; i < 4; ++i) {
            const float dx = v[i].x - mean, dy = v[i].y - mean;
            const float dz = v[i].z - mean, dw = v[i].w - mean;
            q += dx * dx + dy * dy + dz * dz + dw * dw;
        }
        #pragma unroll
        for (int off = 32; off > 0; off >>= 1) q += __shfl_xor(q, off);
        const float var = q * (1.0f / 1024.0f);
        const float rstd = rsqrtf(var + 1e-5f);
        #pragma unroll
        for (int i = 0; i < 4; ++i) {
            scv[i] = ((const float4*)sc)[i * 64 + lane];
            bsv[i] = ((const float4*)bs)[i * 64 + lane];
        }
        #pragma unroll
        for (int i = 0; i < 4; ++i) {
            const u16 o0 = f2bf((v[i].x - mean) * rstd * scv[i].x + bsv[i].x);
            const u16 o1 = f2bf((v[i].y - mean) * rstd * scv[i].y + bsv[i].y);
            const u16 o2 = f2bf((v[i].z - mean) * rstd * scv[i].z + bsv[i].z);
            const u16 o3 = f2bf((v[i].w - mean) * rstd * scv[i].w + bsv[i].w);
            uint2 pk;
            pk.x = (uint32_t)o0 | ((uint32_t)o1 << 16);
            pk.y = (uint32_t)o2 | ((uint32_t)o3 << 16);
            *(uint2*)&zn[(size_t)row * 1024 + (i * 64 + lane) * 4] = pk;
        }
        return;
    }

    const float* in;
    u16* out;
    int N, permute, bx, by;
    if (bid < 1024 + 1536) {               // w_qkv: [1024,3072] -> permuted [3072,1024]
        const int r = bid - 1024;
        in = w_qkv; out = wqkvT; N = 3072; permute = 1;
        bx = r % 48; by = r / 48;
    } else {                               // w_proj: [1024,1024] -> [1024,1024]
        const int r = bid - 1024 - 1536;
        in = w_proj; out = wprojT; N = 1024; permute = 0;
        bx = r % 16; by = r / 16;
    }
    const int kb = by * 32, nb = bx * 64;
    const int lr = tid >> 3, lq = tid & 7;
    const float* src = &in[(size_t)(kb + lr) * N + nb + lq * 8];
    const float4 va = *(const float4*)src;
    const float4 vb = *(const float4*)(src + 4);
    *(float4*)&t[lr][lq * 8] = va;
    *(float4*)&t[lr][lq * 8 + 4] = vb;
    __syncthreads();
    const int cj = tid >> 6, c = tid & 63;
    const int col = nb + c;
    int np = col;
    if (permute) {
        const int h = col / 192, rem = col - h * 192;
        const int d = rem / 3, s = rem - d * 3;
        np = s * 1024 + h * 64 + d;
    }
    u16 pk[8];
    #pragma unroll
    for (int u = 0; u < 8; ++u) pk[u] = f2bf(t[cj * 8 + u][c]);
    *(uint4*)&out[(size_t)np * 1024 + kb + cj * 8] = *(const uint4*)pk;
}

// ---------------- GEMM1 — R24: BK=64 (half the barrier drains) -------------
// Pre-swizzled-source staging (rule #21): stage global chunk gc8^gr8 into
// linear LDS chunk gc8, read chunk (kk*4+quad)^(l16&7) — XORs cancel,
// conflict-free. HW-verified correct in R9 (absmax unchanged).
__global__ __launch_bounds__(256, 3) void gemm_qkv(const u16* __restrict__ A,
                                                   const u16* __restrict__ Bt,
                                                   u16* __restrict__ qbuf,
                                                   u16* __restrict__ kbuf,
                                                   u16* __restrict__ vT) {
    __shared__ __align__(16) u16 sm[16384];      // As 128*64 | Bs 128*64 (32 KB)
    u16* const As = sm;
    u16* const Bs = sm + 8192;
    const int tid = threadIdx.x;
    const int wave = tid >> 6, lane = tid & 63;
    const int quad = lane >> 4, l16 = lane & 15;
    const int wm = (wave >> 1) * 64, wn = (wave & 1) * 64;
    const int lin = blockIdx.y * 32 + blockIdx.x;           // 0..767
    const int nlin = (lin & 7) * 96 + (lin >> 3);           // bijective (768%8==0)
    const int bxs = nlin & 31, bys = nlin >> 5;
    const int row0 = bxs * 128, col0 = bys * 128;
    const int gr8 = lane >> 3, gc8 = lane & 7;
    const int sca = (gc8 ^ gr8) * 8;             // pre-swizzled source column
    f32x4 acc[4][4] = {};
    for (int kt = 0; kt < 1024; kt += 64) {
        __syncthreads();
        #pragma unroll
        for (int j = 0; j < 4; ++j) {
            const int rb = wave * 8 + j * 32;
            gload_lds16(&A[(size_t)(row0 + rb + gr8) * 1024 + kt + sca], &As[rb * 64]);
            gload_lds16(&Bt[(size_t)(col0 + rb + gr8) * 1024 + kt + sca], &Bs[rb * 64]);
        }
        __syncthreads();
        #pragma unroll
        for (int kk = 0; kk < 2; ++kk) {
            bf16x8 ax[4], bx[4];
            #pragma unroll
            for (int t = 0; t < 4; ++t) {
                const int ar = wm + t * 16 + l16;
                ax[t] = *(const bf16x8*)&As[ar * 64 + (((kk * 4 + quad) ^ (l16 & 7)) << 3)];
                const int br = wn + t * 16 + l16;
                bx[t] = *(const bf16x8*)&Bs[br * 64 + (((kk * 4 + quad) ^ (l16 & 7)) << 3)];
            }
            #pragma unroll
            for (int mt = 0; mt < 4; ++mt)
                #pragma unroll
                for (int nt = 0; nt < 4; ++nt)
                    acc[mt][nt] = __builtin_amdgcn_mfma_f32_16x16x32_bf16(ax[mt], bx[nt], acc[mt][nt], 0, 0, 0);
        }
    }
    const int s = col0 >> 10;                 // block-uniform
    if (s < 2) {
        u16* const dst = (s == 0) ? qbuf : kbuf;
        const float scl = (s == 0) ? 0.125f * 1.44269504088896f : 1.0f;
        #pragma unroll
        for (int mt = 0; mt < 4; ++mt) {
            #pragma unroll
            for (int nt = 0; nt < 4; ++nt) {
                #pragma unroll
                for (int e = 0; e < 4; ++e) {
                    const int row = row0 + wm + mt * 16 + quad * 4 + e;
                    const int col = col0 + wn + nt * 16 + l16;
                    const int b = row >> 11, n = row & 2047;
                    const int h = (col >> 6) & 15, d = col & 63;
                    dst[((size_t)(b * 16 + h) * 2048 + n) * 64 + d] = f2bf(acc[mt][nt][e] * scl);
                }
            }
        }
    } else {
        // V: transpose 128x128 tile through LDS, store to vT[bh,d,n].
        const int b = row0 >> 11, n0 = row0 & 2047;
        const int h0 = (col0 >> 6) & 15;          // col0 = 2048 + cb*128 -> h0 = 2*cb
        for (int hh = 0; hh < 2; ++hh) {
            __syncthreads();                      // tile buffer free (main loop / prev pass done)
            if ((wave & 1) == hh) {               // wn == hh*64 waves own this col-half
                #pragma unroll
                for (int mt = 0; mt < 4; ++mt) {
                    const int rl = wm + mt * 16 + quad * 4;       // multiple of 4 -> 8B aligned
                    #pragma unroll
                    for (int nt = 0; nt < 4; ++nt) {
                        const int cl = nt * 16 + l16;             // d 0..63
                        u16 tmp[4];
                        #pragma unroll
                        for (int e = 0; e < 4; ++e) tmp[e] = f2bf(acc[mt][nt][e]);
                        *(uint2*)&sm[cl * 136 + rl] = *(const uint2*)tmp;   // ds_write_b64
                    }
                }
            }
            __syncthreads();
            const int bh = b * 16 + h0 + hh;
            #pragma unroll
            for (int pass = 0; pass < 4; ++pass) {
                const int chunk = pass * 256 + tid;   // 0..1023
                const int d = chunk >> 4;             // 0..63
                const int nc = chunk & 15;            // 16 chunks of 8 n
                const uint4 vv = *(const uint4*)&sm[d * 136 + nc * 8];
                *(uint4*)&vT[((size_t)bh * 64 + d) * 2048 + n0 + nc * 8] = vv;
            }
        }
    }
}

// -------- Fused flash attention (R23 2-deep S-pipeline, kept) --------------
// 41.8-44.4us across runs (noise +-3) = ~91% of documented plain-HIP attn
// ceiling (~900 TF, m214). Kept as-is.
__global__ __launch_bounds__(256, 2) void attn_kernel(const u16* __restrict__ qb,
                                                      const u16* __restrict__ kb,
                                                      const u16* __restrict__ vT,
                                                      u16* __restrict__ att_out) {
    __shared__ __align__(16) u16 smem[3 * 8192];   // 3 bufs: [Ks 64*64 | Vs 64*64]
    const int tid = threadIdx.x;
    const int wave = tid >> 6, lane = tid & 63;
    const int quad = lane >> 4, l16 = lane & 15;
    const int lin = blockIdx.y * 16 + blockIdx.x;          // 0..511
    const int nlin = (lin & 7) * 64 + (lin >> 3);          // bijective (512%8==0)
    const int qt = nlin & 15, bh = nlin >> 4;
    const int b = bh >> 4, h = bh & 15;

    const u16* qrowA = &qb[(size_t)(bh * 2048 + qt * 128 + wave * 32 + l16) * 64];
    const bf16x8 qA0 = *(const bf16x8*)&qrowA[quad * 8];
    const bf16x8 qA1 = *(const bf16x8*)&qrowA[32 + quad * 8];
    const u16* qrowB = qrowA + 16 * 64;
    const bf16x8 qB0 = *(const bf16x8*)&qrowB[quad * 8];
    const bf16x8 qB1 = *(const bf16x8*)&qrowB[32 + quad * 8];

    const u16* ksrc[2];
    const u16* vsrc[2];
    int kofs[2], vofs[2];
    #pragma unroll
    for (int j = 0; j < 2; ++j) {
        const int p = 8 * wave + 32 * j + (lane >> 3);      // 0..63
        const int kr = (p & 0x60) | ((p & 12) << 1) | ((p & 16) >> 2) | (p & 3);
        const int gk = (lane & 7) ^ (p & 7);
        ksrc[j] = kb + ((size_t)bh * 2048 + kr) * 64 + gk * 8;
        kofs[j] = (8 * wave + 32 * j) * 64;
        const int d = 8 * wave + 32 * j + (lane >> 3);      // 0..63
        const int gv = (lane & 7) ^ ((d >> 1) & 7);
        vsrc[j] = vT + ((size_t)bh * 64 + d) * 2048 + gv * 8;
        vofs[j] = 4096 + (8 * wave + 32 * j) * 64;
    }

    f32x4 oA[4] = {}, oB[4] = {};
    f32x4 lA = {}, lB = {};
    f32x4 s0A[4], s0B[4], s1A[4], s1B[4];
    bf16x8 ones;
    #pragma unroll
    for (int i = 0; i < 8; ++i) ones[i] = (__bf16)1.0f;

    auto stage = [&](int buf) {
        u16* dst = smem + buf * 8192;
        #pragma unroll
        for (int j = 0; j < 2; ++j) {
            gload_lds16(ksrc[j], dst + kofs[j]);
            gload_lds16(vsrc[j], dst + vofs[j]);
            ksrc[j] += 64 * 64;
            vsrc[j] += 64;
        }
    };
    auto QK = [&](int buf, f32x4 (&sA)[4], f32x4 (&sB)[4]) {
        const u16* Ks = smem + buf * 8192;
        #pragma unroll
        for (int nt = 0; nt < 4; ++nt) {
            const int r = nt * 16 + l16;
            const bf16x8 k0 = *(const bf16x8*)&Ks[r * 64 + (((quad) ^ (r & 7)) << 3)];
            const bf16x8 k1 = *(const bf16x8*)&Ks[r * 64 + (((quad + 4) ^ (r & 7)) << 3)];
            f32x4 a = {}, c = {};
            a = __builtin_amdgcn_mfma_f32_16x16x32_bf16(k0, qA0, a, 0, 0, 0);
            a = __builtin_amdgcn_mfma_f32_16x16x32_bf16(k1, qA1, a, 0, 0, 0);
            c = __builtin_amdgcn_mfma_f32_16x16x32_bf16(k0, qB0, c, 0, 0, 0);
            c = __builtin_amdgcn_mfma_f32_16x16x32_bf16(k1, qB1, c, 0, 0, 0);
            sA[nt] = a;
            sB[nt] = c;
        }
    };
    auto EXPPV = [&](int buf, f32x4 (&sA)[4], f32x4 (&sB)[4]) {
        bf16x8 apA[2], apB[2];
        #pragma unroll
        for (int nt = 0; nt < 4; ++nt)
            #pragma unroll
            for (int e = 0; e < 4; ++e) {
                apA[nt >> 1][(nt & 1) * 4 + e] = (__bf16)__builtin_amdgcn_exp2f(sA[nt][e]);
                apB[nt >> 1][(nt & 1) * 4 + e] = (__bf16)__builtin_amdgcn_exp2f(sB[nt][e]);
            }
        const u16* Vs = smem + buf * 8192 + 4096;
        #pragma unroll
        for (int vt = 0; vt < 4; ++vt) {
            const int dd = vt * 16 + l16;
            #pragma unroll
            for (int c = 0; c < 2; ++c) {
                const bf16x8 vf = *(const bf16x8*)&Vs[dd * 64 + (((c * 4 + quad) ^ ((dd >> 1) & 7)) << 3)];
                oA[vt] = __builtin_amdgcn_mfma_f32_16x16x32_bf16(apA[c], vf, oA[vt], 0, 0, 0);
                oB[vt] = __builtin_amdgcn_mfma_f32_16x16x32_bf16(apB[c], vf, oB[vt], 0, 0, 0);
            }
        }
        #pragma unroll
        for (int c = 0; c < 2; ++c) {
            lA = __builtin_amdgcn_mfma_f32_16x16x32_bf16(apA[c], ones, lA, 0, 0, 0);
            lB = __builtin_amdgcn_mfma_f32_16x16x32_bf16(apB[c], ones, lB, 0, 0, 0);
        }
    };

    stage(0);
    stage(1);
    __syncthreads();
    QK(0, s0A, s0B);

    int bPrev = 0, bCur = 1, bNext = 2;
    #pragma unroll 1
    for (int tp = 0; tp < 15; ++tp) {
        __syncthreads();
        stage(bNext);
        __builtin_amdgcn_s_setprio(1);
        QK(bCur, s1A, s1B);
        EXPPV(bPrev, s0A, s0B);
        __builtin_amdgcn_s_setprio(0);
        bPrev = bCur; bCur = bNext; bNext = (bNext == 2) ? 0 : bNext + 1;
        __syncthreads();
        stage(bNext);
        __builtin_amdgcn_s_setprio(1);
        QK(bCur, s0A, s0B);
        EXPPV(bPrev, s1A, s1B);
        __builtin_amdgcn_s_setprio(0);
        bPrev = bCur; bCur = bNext; bNext = (bNext == 2) ? 0 : bNext + 1;
    }
    __syncthreads();
    __builtin_amdgcn_s_setprio(1);
    QK(bCur, s1A, s1B);
    EXPPV(bPrev, s0A, s0B);
    EXPPV(bCur, s1A, s1B);
    __builtin_amdgcn_s_setprio(0);

    #pragma unroll
    for (int e = 0; e < 4; ++e) {
        const float invA = 1.0f / lA[e];
        const float invB = 1.0f / lB[e];
        const int nA = qt * 128 + wave * 32 + quad * 4 + e;
        #pragma unroll
        for (int vt = 0; vt < 4; ++vt) {
            att_out[(size_t)(b * 2048 + nA) * 1024 + h * 64 + vt * 16 + l16] = f2bf(oA[vt][e] * invA);
            att_out[(size_t)(b * 2048 + nA + 16) * 1024 + h * 64 + vt * 16 + l16] = f2bf(oB[vt][e] * invB);
        }
    }
}

// ---- GEMM2 — R25: BK=64 (same HW-verified pattern as gemm_qkv R24) --------
// Halves barrier drains (32->16). Pre-swizzled source + XOR read, 0-conflict.
// Epilogue unchanged: + bias + z residual, fp32 out. XCD swizzle kept.
__global__ __launch_bounds__(256, 3) void gemm_proj(const u16* __restrict__ A,
                                                    const u16* __restrict__ Bt,
                                                    const float* __restrict__ bias,
                                                    const float* __restrict__ z,
                                                    float* __restrict__ out) {
    __shared__ __align__(16) u16 sm[16384];      // As 128*64 | Bs 128*64 (32 KB)
    u16* const As = sm;
    u16* const Bs = sm + 8192;
    const int tid = threadIdx.x;
    const int wave = tid >> 6, lane = tid & 63;
    const int quad = lane >> 4, l16 = lane & 15;
    const int wm = (wave >> 1) * 64, wn = (wave & 1) * 64;
    const int lin = blockIdx.y * 32 + blockIdx.x;          // 0..255
    const int nlin = (lin & 7) * 32 + (lin >> 3);          // bijective (256%8==0)
    const int bxs = nlin & 31, bys = nlin >> 5;
    const int row0 = bxs * 128, col0 = bys * 128;
    const int gr8 = lane >> 3, gc8 = lane & 7;
    const int sca = (gc8 ^ gr8) * 8;
    f32x4 acc[4][4] = {};
    for (int kt = 0; kt < 1024; kt += 64) {
        __syncthreads();
        #pragma unroll
        for (int j = 0; j < 4; ++j) {
            const int rb = wave * 8 + j * 32;
            gload_lds16(&A[(size_t)(row0 + rb + gr8) * 1024 + kt + sca], &As[rb * 64]);
            gload_lds16(&Bt[(size_t)(col0 + rb + gr8) * 1024 + kt + sca], &Bs[rb * 64]);
        }
        __syncthreads();
        #pragma unroll
        for (int kk = 0; kk < 2; ++kk) {
            bf16x8 ax[4], bx[4];
            #pragma unroll
            for (int t = 0; t < 4; ++t) {
                const int ar = wm + t * 16 + l16;
                ax[t] = *(const bf16x8*)&As[ar * 64 + (((kk * 4 + quad) ^ (l16 & 7)) << 3)];
                const int br = wn + t * 16 + l16;
                bx[t] = *(const bf16x8*)&Bs[br * 64 + (((kk * 4 + quad) ^ (l16 & 7)) << 3)];
            }
            #pragma unroll
            for (int mt = 0; mt < 4; ++mt)
                #pragma unroll
                for (int nt = 0; nt < 4; ++nt)
                    acc[mt][nt] = __builtin_amdgcn_mfma_f32_16x16x32_bf16(ax[mt], bx[nt], acc[mt][nt], 0, 0, 0);
        }
    }
    #pragma unroll
    for (int mt = 0; mt < 4; ++mt) {
        #pragma unroll
        for (int nt = 0; nt < 4; ++nt) {
            #pragma unroll
            for (int e = 0; e < 4; ++e) {
                const int row = row0 + wm + mt * 16 + quad * 4 + e;
                const int col = col0 + wn + nt * 16 + l16;
                out[(size_t)row * 1024 + col] = acc[mt][nt][e] + bias[col] + z[(size_t)row * 1024 + col];
            }
        }
    }
}

extern "C" void kernel_launch(void* const* d_in, const int* in_sizes, int n_in,
                              void* d_out, int out_size, void* d_ws, size_t ws_size,
                              hipStream_t stream) {
    const float* z        = (const float*)d_in[0];
    const float* ln_scale = (const float*)d_in[1];
    const float* ln_bias  = (const float*)d_in[2];
    const float* w_qkv    = (const float*)d_in[3];
    const float* w_proj   = (const float*)d_in[4];
    const float* b_proj   = (const float*)d_in[5];
    float* out = (float*)d_out;

    char* ws = (char*)d_ws;
    u16* zn     = (u16*)(ws);                       // 0-8 MiB   [4096,1024]
    u16* wqkvT  = (u16*)(ws + (8u << 20));          // 8-14 MiB  [3072,1024] (rows permuted)
    u16* wprojT = (u16*)(ws + (14u << 20));         // 14-16 MiB [1024,1024]
    u16* qbuf   = (u16*)(ws + (16u << 20));         // 16-24 MiB [32,2048,64] (pre-scaled 0.125*log2e)
    u16* kbuf   = (u16*)(ws + (24u << 20));         // 24-32 MiB [32,2048,64]
    u16* vT     = (u16*)(ws + (32u << 20));         // 32-40 MiB [32,64,2048] (written by gemm_qkv)
    u16* att_o  = (u16*)(ws + (40u << 20));         // 40-48 MiB [4096,1024]

    prep_kernel<<<dim3(1024 + 1536 + 512), 256, 0, stream>>>(
        z, ln_scale, ln_bias, w_qkv, w_proj, zn, wqkvT, wprojT);
    gemm_qkv<<<dim3(32, 24), 256, 0, stream>>>(zn, wqkvT, qbuf, kbuf, vT);
    attn_kernel<<<dim3(16, 32), 256, 0, stream>>>(qbuf, kbuf, vT, att_o);
    gemm_proj<<<dim3(32, 8), 256, 0, stream>>>(att_o, wprojT, b_proj, z, out);
}